// Round 1
// 85.302 us; speedup vs baseline: 1.0848x; 1.0848x over previous
//
#include <hip/hip_runtime.h>
#include <hip/hip_bf16.h>

#define K_DIM   1024
#define N_OUT   256
#define XY_COLS 2304   // 9*256

typedef __bf16 bf16x8 __attribute__((ext_vector_type(8)));
typedef float  f32x4  __attribute__((ext_vector_type(4)));
typedef float  f32x2  __attribute__((ext_vector_type(2)));

// K1: xy[256][2304] = input @ W^T + b_xy   (fp32 out to workspace)
// Tile BM=32, BN=64, BK=64. Grid 8*36=288 blocks, 256 threads (4 waves).
// Double-buffered LDS, ONE barrier per K-step (16 total vs 63 before).
// LDS rows are 64 bf16 = 128B (all 32 banks) with XOR chunk-swizzle
// chunk' = chunk ^ (row&7)  ->  conflict-free b128 reads AND writes.
__global__ __launch_bounds__(256) void gemm_xy_kernel(
    const float* __restrict__ A,
    const float* __restrict__ W,
    const float* __restrict__ bias,
    float* __restrict__ xy)
{
    const int t   = threadIdx.x;
    const int bid = blockIdx.x;
    const int mt  = bid / 36;
    const int nt  = bid - mt * 36;
    const int m0  = mt * 32;
    const int n0  = nt * 64;

    __shared__ __align__(16) __bf16 sA[2][32][64];   // 8 KB
    __shared__ __align__(16) __bf16 sB[2][64][64];   // 16 KB

    // staging: A-tile 32x64 (8 fp32/thread), W-tile 64x64 (16 fp32/thread)
    const int ra = t >> 3;          // 0..31
    const int ka = (t & 7) * 8;     // 0..56
    const int rw = t >> 2;          // 0..63
    const int kw = (t & 3) * 16;    // 0,16,32,48

    const float* pA = A + (m0 + ra) * K_DIM + ka;
    const float* pW = W + (n0 + rw) * K_DIM + kw;

    // swizzled store columns (element index, 8-elem = 16B chunks)
    const int kaS  = ka ^ ((ra & 7) * 8);
    const int kwS0 = kw ^ ((rw & 7) * 8);
    const int kwS1 = (kw + 8) ^ ((rw & 7) * 8);

    const int lane = t & 63;
    const int wv   = t >> 6;
    const int mh   = wv >> 1;
    const int nh   = wv & 1;
    const int l15  = lane & 15;
    const int quad = lane >> 4;

    const int arow  = 16 * mh + l15;
    const int brow0 = 32 * nh + l15;
    const int brow1 = brow0 + 16;          // (brow1&7)==(brow0&7)
    const int aswz  = (arow & 7) * 8;
    const int bswz  = (brow0 & 7) * 8;

    f32x4 acc0 = {0.f, 0.f, 0.f, 0.f};
    f32x4 acc1 = {0.f, 0.f, 0.f, 0.f};

    float4 rA[2][2], rW[2][4];
    rA[0][0] = *(const float4*)(pA);
    rA[0][1] = *(const float4*)(pA + 4);
    rW[0][0] = *(const float4*)(pW);
    rW[0][1] = *(const float4*)(pW + 4);
    rW[0][2] = *(const float4*)(pW + 8);
    rW[0][3] = *(const float4*)(pW + 12);

    #pragma unroll
    for (int kk = 0; kk < 16; ++kk) {
        const int buf = kk & 1;
        const int nxt = buf ^ 1;
        if (kk + 1 < 16) {                       // issue next slab FIRST (vmcnt(6) wait on current)
            const float* qA = pA + (kk + 1) * 64;
            const float* qW = pW + (kk + 1) * 64;
            rA[nxt][0] = *(const float4*)(qA);
            rA[nxt][1] = *(const float4*)(qA + 4);
            rW[nxt][0] = *(const float4*)(qW);
            rW[nxt][1] = *(const float4*)(qW + 4);
            rW[nxt][2] = *(const float4*)(qW + 8);
            rW[nxt][3] = *(const float4*)(qW + 12);
        }
        {
            float4 a0 = rA[buf][0], a1 = rA[buf][1];
            bf16x8 av = { (__bf16)a0.x, (__bf16)a0.y, (__bf16)a0.z, (__bf16)a0.w,
                          (__bf16)a1.x, (__bf16)a1.y, (__bf16)a1.z, (__bf16)a1.w };
            *(bf16x8*)&sA[buf][ra][kaS] = av;
            float4 w0 = rW[buf][0], w1 = rW[buf][1];
            float4 w2 = rW[buf][2], w3 = rW[buf][3];
            bf16x8 wv0 = { (__bf16)w0.x, (__bf16)w0.y, (__bf16)w0.z, (__bf16)w0.w,
                           (__bf16)w1.x, (__bf16)w1.y, (__bf16)w1.z, (__bf16)w1.w };
            bf16x8 wv1 = { (__bf16)w2.x, (__bf16)w2.y, (__bf16)w2.z, (__bf16)w2.w,
                           (__bf16)w3.x, (__bf16)w3.y, (__bf16)w3.z, (__bf16)w3.w };
            *(bf16x8*)&sB[buf][rw][kwS0] = wv0;
            *(bf16x8*)&sB[buf][rw][kwS1] = wv1;
        }
        __syncthreads();   // single barrier per step: writes(buf) above, reads(buf) below
        bf16x8 af0 = *(const bf16x8*)&sA[buf][arow][(quad * 8)      ^ aswz];
        bf16x8 af1 = *(const bf16x8*)&sA[buf][arow][(32 + quad * 8) ^ aswz];
        bf16x8 b00 = *(const bf16x8*)&sB[buf][brow0][(quad * 8)      ^ bswz];
        bf16x8 b01 = *(const bf16x8*)&sB[buf][brow0][(32 + quad * 8) ^ bswz];
        bf16x8 b10 = *(const bf16x8*)&sB[buf][brow1][(quad * 8)      ^ bswz];
        bf16x8 b11 = *(const bf16x8*)&sB[buf][brow1][(32 + quad * 8) ^ bswz];
        acc0 = __builtin_amdgcn_mfma_f32_16x16x32_bf16(af0, b00, acc0, 0, 0, 0);
        acc0 = __builtin_amdgcn_mfma_f32_16x16x32_bf16(af1, b01, acc0, 0, 0, 0);
        acc1 = __builtin_amdgcn_mfma_f32_16x16x32_bf16(af0, b10, acc1, 0, 0, 0);
        acc1 = __builtin_amdgcn_mfma_f32_16x16x32_bf16(af1, b11, acc1, 0, 0, 0);
    }

    // C/D layout: col = lane&15, row = quad*4 + reg
    const int row0 = m0 + 16 * mh + quad * 4;
    const int col0 = n0 + 32 * nh + l15;
    const float b0 = bias[col0];
    const float b1 = bias[col0 + 16];
    #pragma unroll
    for (int r = 0; r < 4; ++r) {
        xy[(row0 + r) * XY_COLS + col0]      = acc0[r] + b0;
        xy[(row0 + r) * XY_COLS + col0 + 16] = acc1[r] + b1;
    }
}

// K2: per batch b: S[c][j] = sum_i exp(x_c[i]) * exp(y_c[i^j])
//     out[b][j] = sum_c w_out[c]*log(S[c][j]) + w_out[4]*skip[j] + b_out
// Grid 256 blocks, 512 threads (8 waves). Wave wv -> copy c=wv>>1, i-half h=wv&1.
// Inner loop reworked to f32x2 pairs -> v_pk_fma_f32 (8 packed vs 16 scalar FMA).
__global__ __launch_bounds__(512) void softxor_kernel(
    const float* __restrict__ xy,
    const float* __restrict__ w_out,
    const float* __restrict__ b_out,
    float* __restrict__ out)
{
    const int b = blockIdx.x;
    const int t = threadIdx.x;

    __shared__ __align__(16) float ex[4][N_OUT];
    __shared__ __align__(16) float ey[4][N_OUT];
    __shared__ __align__(16) float sk[N_OUT];
    __shared__ __align__(16) float part[8][N_OUT];

    const float* row = xy + (long)b * XY_COLS;

    for (int e4 = t; e4 < XY_COLS / 4; e4 += 512) {
        float4 v = *(const float4*)(row + e4 * 4);
        int e = e4 * 4;
        if (e < 1024) {
            float* d = &ex[e >> 8][e & 255];
            d[0] = __expf(v.x); d[1] = __expf(v.y); d[2] = __expf(v.z); d[3] = __expf(v.w);
        } else if (e < 2048) {
            float* d = &ey[(e >> 8) - 4][e & 255];
            d[0] = __expf(v.x); d[1] = __expf(v.y); d[2] = __expf(v.z); d[3] = __expf(v.w);
        } else {
            float* d = &sk[e - 2048];
            d[0] = v.x; d[1] = v.y; d[2] = v.z; d[3] = v.w;
        }
    }
    __syncthreads();

    const int wv = t >> 6;
    const int c  = wv >> 1;
    const int h  = wv & 1;
    const int jh = t & 63;

    f32x2 s01 = {0.f, 0.f};
    f32x2 s23 = {0.f, 0.f};
    const int ih0 = h * 32;
    #pragma unroll 4
    for (int ih = ih0; ih < ih0 + 32; ++ih) {
        float4 xa = *(const float4*)&ex[c][ih * 4];            // broadcast
        float4 yb = *(const float4*)&ey[c][(ih ^ jh) * 4];     // permuted gather (conflict-free)
        f32x2 yp0  = { yb.x, yb.y };
        f32x2 yp0s = { yb.y, yb.x };
        f32x2 yp1  = { yb.z, yb.w };
        f32x2 yp1s = { yb.w, yb.z };
        f32x2 xx = { xa.x, xa.x };
        f32x2 xy2 = { xa.y, xa.y };
        f32x2 xz = { xa.z, xa.z };
        f32x2 xw = { xa.w, xa.w };
        s01 += xx  * yp0;    // S0 += x.x*y.x ; S1 += x.x*y.y
        s01 += xy2 * yp0s;   // S0 += x.y*y.y ; S1 += x.y*y.x
        s01 += xz  * yp1;    // S0 += x.z*y.z ; S1 += x.z*y.w
        s01 += xw  * yp1s;   // S0 += x.w*y.w ; S1 += x.w*y.z
        s23 += xx  * yp1;    // S2 += x.x*y.z ; S3 += x.x*y.w
        s23 += xy2 * yp1s;   // S2 += x.y*y.w ; S3 += x.y*y.z
        s23 += xz  * yp0;    // S2 += x.z*y.x ; S3 += x.z*y.y
        s23 += xw  * yp0s;   // S2 += x.w*y.y ; S3 += x.w*y.x
    }
    *(float4*)&part[wv][jh * 4] = make_float4(s01.x, s01.y, s23.x, s23.y);
    __syncthreads();

    if (t < N_OUT) {
        float acc = w_out[4] * sk[t] + b_out[0];
        #pragma unroll
        for (int cc = 0; cc < 4; ++cc) {
            float S = part[2 * cc][t] + part[2 * cc + 1][t];
            acc += w_out[cc] * __logf(S);
        }
        out[b * N_OUT + t] = acc;
    }
}

extern "C" void kernel_launch(void* const* d_in, const int* in_sizes, int n_in,
                              void* d_out, int out_size, void* d_ws, size_t ws_size,
                              hipStream_t stream) {
    const float* input = (const float*)d_in[0];
    const float* W_xy  = (const float*)d_in[1];
    const float* b_xy  = (const float*)d_in[2];
    const float* w_out = (const float*)d_in[3];
    const float* b_out = (const float*)d_in[4];
    float* outp = (float*)d_out;
    float* xy   = (float*)d_ws;   // 256*2304*4 = 2.36 MB

    gemm_xy_kernel<<<288, 256, 0, stream>>>(input, W_xy, b_xy, xy);
    softxor_kernel<<<256, 512, 0, stream>>>(xy, w_out, b_out, outp);
}